// Round 6
// baseline (658.119 us; speedup 1.0000x reference)
//
#include <hip/hip_runtime.h>
#include <cstdint>
#include <cstddef>

// Problem constants (fixed by the reference)
#define NATOMS 400000
#define NEDGES 1600000
#define NGRAPH 4096
#define F_INN  78
#define HDIM   128
#define FF0D   256
#define FF1D   128

// layer-0 packed-input row: 78 feats + pad, bf16, 80 slots (160B)
#define XPAD   80

typedef __attribute__((ext_vector_type(8))) short short8;   // 8 bf16 (4 VGPRs)
typedef __attribute__((ext_vector_type(4))) short short4v;  // 4 bf16 (8B store)
typedef __attribute__((ext_vector_type(4))) float f32x4;
typedef __attribute__((ext_vector_type(2))) float f32x2;

// f32 -> bf16 round-to-nearest-even (bit-level)
static __device__ __forceinline__ short f2bf(float f) {
    unsigned u = __builtin_bit_cast(unsigned, f);
    unsigned r = (u + 0x7fffu + ((u >> 16) & 1u)) >> 16;
    return (short)r;
}
static __device__ __forceinline__ float bf2f(unsigned short u) {
    return __builtin_bit_cast(float, ((unsigned)u) << 16);
}

// ---------------- degree + per-edge rank (atomic return value) ----------------
__global__ __launch_bounds__(256) void k_degi(const int* __restrict__ dst,
                                              int* __restrict__ deg,
                                              int* __restrict__ rank, int E) {
    int e = blockIdx.x * 256 + threadIdx.x;
    if (e < E) rank[e] = atomicAdd(&deg[dst[e]], 1);
}

// ---------------- exclusive scan over N ints (3 kernels, in-place) ----------------
// scan1 also emits dinv = rsqrt(deg+1) (deg still intact at entry)
__global__ __launch_bounds__(256) void k_scan1(int* __restrict__ data,
                                               int* __restrict__ blockSums,
                                               float* __restrict__ dinv, int n) {
    __shared__ int ts[256];
    const int base = blockIdx.x * 1024 + threadIdx.x * 4;
    int v[4];
    #pragma unroll
    for (int j = 0; j < 4; ++j) v[j] = (base + j < n) ? data[base + j] : 0;
    #pragma unroll
    for (int j = 0; j < 4; ++j)
        if (base + j < n) dinv[base + j] = rsqrtf((float)v[j] + 1.0f);
    const int tot = v[0] + v[1] + v[2] + v[3];
    ts[threadIdx.x] = tot;
    __syncthreads();
    #pragma unroll
    for (int off = 1; off < 256; off <<= 1) {
        int t = (threadIdx.x >= off) ? ts[threadIdx.x - off] : 0;
        __syncthreads();
        ts[threadIdx.x] += t;
        __syncthreads();
    }
    int run = ts[threadIdx.x] - tot;
    #pragma unroll
    for (int j = 0; j < 4; ++j) {
        if (base + j < n) data[base + j] = run;
        run += v[j];
    }
    if (threadIdx.x == 255) blockSums[blockIdx.x] = ts[255];
}

__global__ __launch_bounds__(512) void k_scan2(int* __restrict__ blockSums, int nb) {
    __shared__ int ts[512];
    int v = (threadIdx.x < nb) ? blockSums[threadIdx.x] : 0;
    ts[threadIdx.x] = v;
    __syncthreads();
    #pragma unroll
    for (int off = 1; off < 512; off <<= 1) {
        int t = (threadIdx.x >= off) ? ts[threadIdx.x - off] : 0;
        __syncthreads();
        ts[threadIdx.x] += t;
        __syncthreads();
    }
    if (threadIdx.x < nb) blockSums[threadIdx.x] = ts[threadIdx.x] - v;
}

__global__ __launch_bounds__(256) void k_scan3(int* __restrict__ data,
                                               const int* __restrict__ blockSums,
                                               int n, int total) {
    const int off = blockSums[blockIdx.x];
    const int base = blockIdx.x * 1024 + threadIdx.x * 4;
    #pragma unroll
    for (int j = 0; j < 4; ++j)
        if (base + j < n) data[base + j] += off;
    if (blockIdx.x == 0 && threadIdx.x == 0) data[n] = total;
}

// ---------------- CSR fill: atomic-free (pos = row_start[d] + rank[e]) ----------
__global__ __launch_bounds__(256) void k_fill(const int* __restrict__ src,
                                              const int* __restrict__ dst,
                                              const int* __restrict__ row_start,
                                              const int* __restrict__ rank,
                                              int2* __restrict__ csr_ev,
                                              const float* __restrict__ dinv, int E) {
    int e = blockIdx.x * 256 + threadIdx.x;
    if (e >= E) return;
    int d = dst[e];
    int s = src[e];
    int pos = row_start[d] + rank[e];
    float norm = dinv[s] * dinv[d];
    csr_ev[pos] = make_int2(s, __builtin_bit_cast(int, norm));
}

// ---------------- weight pack: W [KSRC][128] f32 -> MFMA A-fragment order bf16 ----
// A[feat][k]: lane&15 = feat-within-tile ct, k = kc*32 + (lane>>4)*8 + j
// If BIASROW: k == KSRC takes bias[n] (input rows carry constant 1.0 there).
template<int KC, int KSRC, bool BIASROW>
__global__ __launch_bounds__(64) void k_packw(const float* __restrict__ W,
                                              const float* __restrict__ b,
                                              short* __restrict__ wf) {
    int t = blockIdx.x * 64 + threadIdx.x;      // t = f*64 + lane
    int f = t >> 6, lane = t & 63;
    int ct = f / KC, kc = f % KC;
    int n  = ct * 16 + (lane & 15);
    int k0 = kc * 32 + (lane >> 4) * 8;
    short8 o;
    #pragma unroll
    for (int j = 0; j < 8; ++j) {
        int k = k0 + j;
        float v = 0.f;
        if (k < KSRC) v = W[(size_t)k * 128 + n];
        else if (BIASROW && k == KSRC) v = b[n];
        o[j] = f2bf(v);
    }
    *(short8*)(wf + (size_t)t * 8) = o;
}

// ---------------- x pack: [N][78] f32 -> [N][80] bf16 (slots 78,79 zero) --------
__global__ __launch_bounds__(256) void k_packx(const float* __restrict__ x,
                                               unsigned short* __restrict__ xb) {
    int t = blockIdx.x * 256 + threadIdx.x;     // N*20 tasks, 4 shorts each
    if (t >= NATOMS * 20) return;
    int n = t / 20, g = t % 20;
    const float* xr = x + (size_t)n * F_INN + g * 4;
    short4v o;
    if (g < 19) {
        f32x2 a = *(const f32x2*)(xr);
        f32x2 b = *(const f32x2*)(xr + 2);
        o.x = f2bf(a.x); o.y = f2bf(a.y); o.z = f2bf(b.x); o.w = f2bf(b.y);
    } else {                                    // feats 76,77 + two zero pads
        f32x2 a = *(const f32x2*)(xr);
        o.x = f2bf(a.x); o.y = f2bf(a.y); o.z = 0; o.w = 0;
    }
    *(short4v*)(xb + (size_t)n * XPAD + g * 4) = o;
}

// ---------------- FUSED layer 0: gather-aggregate (78-dim) + MFMA GEMM ----------
// One block = 32 nodes, 256 threads.
// Phase 1 (8 lanes/node): aggx_row = dinv^2*xb[n] + sum_s norm*xb[s] -> LDS tile
//   xs[32][XLDS] bf16 (col 78 = 1.0 bias lane; cols 80..95 zeroed for the kc=2
//   fragment tail). XLDS=104 (208B rows): 16B-aligned, 2-way-conflict max.
// Phase 2 (4 waves): tile T=wid>>1 (16 nodes), ct-half c0=(wid&1)*4. A-fragments
//   ds_read_b128 from xs, W0_aug fragments from LDS (staged once per block),
//   relu epilogue, store via wave-private swizzled 2KB LDS -> 1KB bursts.
// Removes the aggx write+read roundtrip (126 MB) of the unfused pipeline.
__global__ __launch_bounds__(256) void k_fused0(
    const unsigned short* __restrict__ xb, const short* __restrict__ wfrag,
    const int* __restrict__ row_start, const int2* __restrict__ csr_ev,
    const float* __restrict__ dinv, short* __restrict__ outp)
{
    constexpr int XLDS = 104;                          // shorts per xs row (208B)
    __shared__ short lds_w[24 * 64 * 8];               // 24 KB W0 fragments
    __shared__ __align__(16) unsigned short xs[32 * XLDS];   // 6.5 KB
    __shared__ __align__(16) char lds_st[4 * 2048];          // 8 KB store tiles

    const int tid = threadIdx.x;
    // ---- stage W0 fragments (L2-hot broadcast) ----
    #pragma unroll
    for (int it = 0; it < 6; ++it) {
        int t = it * 256 + tid;
        *(short8*)(lds_w + (size_t)t * 8) = *(const short8*)(wfrag + (size_t)t * 8);
    }

    // ---- phase 1: gather-aggregate 32 nodes into xs ----
    {
        const int nl = tid >> 3;               // local node 0..31
        const int n  = blockIdx.x * 32 + nl;
        const int l  = tid & 7;
        const int c8 = l * 8;                  // head feats c8..c8+7
        const int ct = 64 + l * 2;             // tail feats ct, ct+1
        const float dv = dinv[n];
        const float d2 = dv * dv;

        float acc[8], tacc0, tacc1;
        {
            const short8 sv = *(const short8*)(xb + (size_t)n * XPAD + c8);
            const unsigned tv = *(const unsigned*)(xb + (size_t)n * XPAD + ct);
            #pragma unroll
            for (int j = 0; j < 8; ++j) acc[j] = bf2f((unsigned short)sv[j]) * d2;
            tacc0 = bf2f((unsigned short)(tv & 0xffff)) * d2;
            tacc1 = bf2f((unsigned short)(tv >> 16)) * d2;
        }

        const int s0 = row_start[n], s1 = row_start[n + 1];
        int i = s0;
        for (; i + 3 < s1; i += 4) {
            const int2 e0 = csr_ev[i];
            const int2 e1 = csr_ev[i + 1];
            const int2 e2 = csr_ev[i + 2];
            const int2 e3 = csr_ev[i + 3];
            const short8 r0 = *(const short8*)(xb + (size_t)e0.x * XPAD + c8);
            const short8 r1 = *(const short8*)(xb + (size_t)e1.x * XPAD + c8);
            const short8 r2 = *(const short8*)(xb + (size_t)e2.x * XPAD + c8);
            const short8 r3 = *(const short8*)(xb + (size_t)e3.x * XPAD + c8);
            const unsigned t0 = *(const unsigned*)(xb + (size_t)e0.x * XPAD + ct);
            const unsigned t1 = *(const unsigned*)(xb + (size_t)e1.x * XPAD + ct);
            const unsigned t2 = *(const unsigned*)(xb + (size_t)e2.x * XPAD + ct);
            const unsigned t3 = *(const unsigned*)(xb + (size_t)e3.x * XPAD + ct);
            const float w0 = __builtin_bit_cast(float, e0.y);
            const float w1 = __builtin_bit_cast(float, e1.y);
            const float w2 = __builtin_bit_cast(float, e2.y);
            const float w3 = __builtin_bit_cast(float, e3.y);
            #pragma unroll
            for (int j = 0; j < 8; ++j) acc[j] = fmaf(bf2f((unsigned short)r0[j]), w0, acc[j]);
            #pragma unroll
            for (int j = 0; j < 8; ++j) acc[j] = fmaf(bf2f((unsigned short)r1[j]), w1, acc[j]);
            #pragma unroll
            for (int j = 0; j < 8; ++j) acc[j] = fmaf(bf2f((unsigned short)r2[j]), w2, acc[j]);
            #pragma unroll
            for (int j = 0; j < 8; ++j) acc[j] = fmaf(bf2f((unsigned short)r3[j]), w3, acc[j]);
            tacc0 = fmaf(bf2f((unsigned short)(t0 & 0xffff)), w0, tacc0);
            tacc1 = fmaf(bf2f((unsigned short)(t0 >> 16)),    w0, tacc1);
            tacc0 = fmaf(bf2f((unsigned short)(t1 & 0xffff)), w1, tacc0);
            tacc1 = fmaf(bf2f((unsigned short)(t1 >> 16)),    w1, tacc1);
            tacc0 = fmaf(bf2f((unsigned short)(t2 & 0xffff)), w2, tacc0);
            tacc1 = fmaf(bf2f((unsigned short)(t2 >> 16)),    w2, tacc1);
            tacc0 = fmaf(bf2f((unsigned short)(t3 & 0xffff)), w3, tacc0);
            tacc1 = fmaf(bf2f((unsigned short)(t3 >> 16)),    w3, tacc1);
        }
        for (; i < s1; ++i) {
            const int2 e0 = csr_ev[i];
            const short8 r0 = *(const short8*)(xb + (size_t)e0.x * XPAD + c8);
            const unsigned t0 = *(const unsigned*)(xb + (size_t)e0.x * XPAD + ct);
            const float w0 = __builtin_bit_cast(float, e0.y);
            #pragma unroll
            for (int j = 0; j < 8; ++j) acc[j] = fmaf(bf2f((unsigned short)r0[j]), w0, acc[j]);
            tacc0 = fmaf(bf2f((unsigned short)(t0 & 0xffff)), w0, tacc0);
            tacc1 = fmaf(bf2f((unsigned short)(t0 >> 16)),    w0, tacc1);
        }

        short8 o;
        #pragma unroll
        for (int j = 0; j < 8; ++j) o[j] = f2bf(acc[j]);
        *(short8*)(xs + nl * XLDS + c8) = o;
        unsigned to;
        if (l == 7) to = 0x00003F80u;      // slot78 = bf16(1.0), slot79 = 0
        else {
            to = (unsigned)(unsigned short)f2bf(tacc0) |
                 ((unsigned)(unsigned short)f2bf(tacc1) << 16);
        }
        *(unsigned*)(xs + nl * XLDS + ct) = to;
        *(unsigned*)(xs + nl * XLDS + 80 + l * 2) = 0u;   // zero k=80..95 (kc=2 tail)
    }
    __syncthreads();

    // ---- phase 2: MFMA ----
    const int lane = tid & 63;
    const int wid  = tid >> 6;
    const int m = lane & 15, q = lane >> 4;
    const int T  = wid >> 1;               // 16-node tile 0/1
    const int c0 = (wid & 1) * 4;          // ct half

    short8 afr[3];
    #pragma unroll
    for (int kc = 0; kc < 3; ++kc)
        afr[kc] = *(const short8*)(xs + (T * 16 + m) * XLDS + kc * 32 + q * 8);

    f32x4 acc[4];
    #pragma unroll
    for (int cc = 0; cc < 4; ++cc) acc[cc] = (f32x4){0.f, 0.f, 0.f, 0.f};
    #pragma unroll
    for (int kc = 0; kc < 3; ++kc)
        #pragma unroll
        for (int cc = 0; cc < 4; ++cc) {
            const short8 wv = *(const short8*)(lds_w + ((size_t)(((c0 + cc) * 3 + kc) * 64 + lane)) * 8);
            acc[cc] = __builtin_amdgcn_mfma_f32_16x16x32_bf16(wv, afr[kc], acc[cc], 0, 0, 0);
        }

    // relu + bf16, wave-private swizzled store tile, then 2x 1KB bursts
    char* const st = lds_st + wid * 2048;
    #pragma unroll
    for (int cc = 0; cc < 4; ++cc) {
        short4v o;
        o.x = f2bf(fmaxf(acc[cc][0], 0.f));
        o.y = f2bf(fmaxf(acc[cc][1], 0.f));
        o.z = f2bf(fmaxf(acc[cc][2], 0.f));
        o.w = f2bf(fmaxf(acc[cc][3], 0.f));
        const int c = (cc * 32 + q * 8) ^ ((m & 7) << 4);
        *(short4v*)(st + m * 128 + c) = o;
    }
    #pragma unroll
    for (int p = 0; p < 2; ++p) {
        const int r  = p * 8 + (lane >> 3);
        const int cb = ((lane & 7) * 16) ^ ((r & 7) << 4);
        const short8 v = *(const short8*)(st + r * 128 + cb);
        *(short8*)(outp + (size_t)(blockIdx.x * 32 + T * 16 + r) * 128
                        + c0 * 16 + (lane & 7) * 8) = v;
    }
}

// ---------------- persistent MFMA GEMM: out[M,128] = in[M,KSRC] @ W (bf16 out) ----
// (layer 1 only now.) 1024 blocks; weights staged to LDS once; 1-deep prefetch;
// LDS store-transpose epilogue (4x contiguous 1KB bursts).
template<int KC, int KSRC, bool RELU>
__global__ __launch_bounds__(256) void k_gemm_mfma(
    const short* __restrict__ inv, const short* __restrict__ wfrag,
    short* __restrict__ outp, int M)
{
    constexpr int NFRAG = 8 * KC;               // fragments (ct x kc)
    __shared__ short lds_w[NFRAG * 64 * 8];     // KC=4: 32 KB
    __shared__ __align__(16) char lds_st[4 * 4096];   // 4 waves x 16 rows x 256B

    const int tid = threadIdx.x;
    #pragma unroll
    for (int it = 0; it < NFRAG * 64 / 256; ++it) {
        int t = it * 256 + tid;
        *(short8*)(lds_w + (size_t)t * 8) = *(const short8*)(wfrag + (size_t)t * 8);
    }
    __syncthreads();

    const int lane = tid & 63;
    const int m = lane & 15, q = lane >> 4;
    const int wid = tid >> 6;
    const int gw = blockIdx.x * 4 + wid;            // global wave id
    const int NW = gridDim.x * 4;                   // total waves
    const int NTILE = M / 16;
    char* const st = lds_st + wid * 4096;           // wave-private store tile

    auto tile_mma = [&](int t, const short8* afr) {
        f32x4 acc[8];
        #pragma unroll
        for (int ct = 0; ct < 8; ++ct) acc[ct] = (f32x4){0.f, 0.f, 0.f, 0.f};
        #pragma unroll
        for (int kc = 0; kc < KC; ++kc)
            #pragma unroll
            for (int ct = 0; ct < 8; ++ct) {
                const short8 wv = *(const short8*)(lds_w + ((size_t)((ct * KC + kc) * 64 + lane)) * 8);
                acc[ct] = __builtin_amdgcn_mfma_f32_16x16x32_bf16(wv, afr[kc], acc[ct], 0, 0, 0);
            }
        #pragma unroll
        for (int ct = 0; ct < 8; ++ct) {
            short4v o;
            float v0 = acc[ct][0], v1 = acc[ct][1], v2 = acc[ct][2], v3 = acc[ct][3];
            if constexpr (RELU) {
                v0 = fmaxf(v0, 0.f); v1 = fmaxf(v1, 0.f);
                v2 = fmaxf(v2, 0.f); v3 = fmaxf(v3, 0.f);
            }
            o.x = f2bf(v0); o.y = f2bf(v1); o.z = f2bf(v2); o.w = f2bf(v3);
            const int c = (ct * 32 + q * 8) ^ ((m & 7) << 4);
            *(short4v*)(st + m * 256 + c) = o;
        }
        #pragma unroll
        for (int p = 0; p < 4; ++p) {
            const int r = p * 4 + (lane >> 4);
            const int c = ((lane & 15) * 16) ^ ((r & 7) << 4);
            const short8 v = *(const short8*)(st + r * 256 + c);
            *(short8*)(outp + (size_t)(t * 16 + r) * 128 + (lane & 15) * 8) = v;
        }
    };

    short8 fA[KC], fB[KC];
    auto load_to = [&](int tile, short8* b) {
        const short* xr = inv + (size_t)(tile * 16 + m) * KSRC;
        #pragma unroll
        for (int kc = 0; kc < KC; ++kc) {
            const int k0 = kc * 32 + q * 8;
            short8 v = {0, 0, 0, 0, 0, 0, 0, 0};
            if (k0 + 8 <= KSRC) v = *(const short8*)(xr + k0);
            b[kc] = v;
        }
    };

    load_to(gw, fA);
    for (int t = gw; t < NTILE; t += NW) {
        const int tn = t + NW;
        if (tn < NTILE) load_to(tn, fB);        // in flight during MFMAs
        tile_mma(t, fA);
        #pragma unroll
        for (int kc = 0; kc < KC; ++kc) fA[kc] = fB[kc];
    }
}

// ---------------- gather aggregation + fused max-pool (layer 1 epilogue) --------
// Two sequential launches (half=0,1): 51.2 MB hot set per pass.
__global__ __launch_bounds__(256) void k_gather_pool(
    const unsigned short* __restrict__ hw,
    const int* __restrict__ row_start, const int2* __restrict__ csr_ev,
    const float* __restrict__ dinv, const float* __restrict__ bias,
    const int* __restrict__ batch, int* __restrict__ pool, int half)
{
    const int n  = blockIdx.x * 32 + (threadIdx.x >> 3);
    const int c8 = half * 64 + (threadIdx.x & 7) * 8;     // feature base
    const float dv = dinv[n];
    const float d2 = dv * dv;

    float acc[8];
    {
        const short8 sv = *(const short8*)(hw + (size_t)n * HDIM + c8);
        #pragma unroll
        for (int j = 0; j < 8; ++j)
            acc[j] = fmaf(bf2f((unsigned short)sv[j]), d2, bias[c8 + j]);
    }

    const int s0 = row_start[n], s1 = row_start[n + 1];
    int i = s0;
    for (; i + 3 < s1; i += 4) {
        const int2 e0 = csr_ev[i];
        const int2 e1 = csr_ev[i + 1];
        const int2 e2 = csr_ev[i + 2];
        const int2 e3 = csr_ev[i + 3];
        const short8 r0 = *(const short8*)(hw + (size_t)e0.x * HDIM + c8);
        const short8 r1 = *(const short8*)(hw + (size_t)e1.x * HDIM + c8);
        const short8 r2 = *(const short8*)(hw + (size_t)e2.x * HDIM + c8);
        const short8 r3 = *(const short8*)(hw + (size_t)e3.x * HDIM + c8);
        const float w0 = __builtin_bit_cast(float, e0.y);
        const float w1 = __builtin_bit_cast(float, e1.y);
        const float w2 = __builtin_bit_cast(float, e2.y);
        const float w3 = __builtin_bit_cast(float, e3.y);
        #pragma unroll
        for (int j = 0; j < 8; ++j) acc[j] = fmaf(bf2f((unsigned short)r0[j]), w0, acc[j]);
        #pragma unroll
        for (int j = 0; j < 8; ++j) acc[j] = fmaf(bf2f((unsigned short)r1[j]), w1, acc[j]);
        #pragma unroll
        for (int j = 0; j < 8; ++j) acc[j] = fmaf(bf2f((unsigned short)r2[j]), w2, acc[j]);
        #pragma unroll
        for (int j = 0; j < 8; ++j) acc[j] = fmaf(bf2f((unsigned short)r3[j]), w3, acc[j]);
    }
    for (; i < s1; ++i) {
        const int2 e0 = csr_ev[i];
        const short8 r0 = *(const short8*)(hw + (size_t)e0.x * HDIM + c8);
        const float w0 = __builtin_bit_cast(float, e0.y);
        #pragma unroll
        for (int j = 0; j < 8; ++j) acc[j] = fmaf(bf2f((unsigned short)r0[j]), w0, acc[j]);
    }

    // ---- fused graph max-pool ----
    const int gbase = batch[blockIdx.x * 32];           // uniform broadcast
    const int glast = batch[blockIdx.x * 32 + 31];      // uniform broadcast
    const int idx   = batch[n] - gbase;                 // 0 or 1

    float red[2][8];
    #pragma unroll
    for (int s = 0; s < 2; ++s)
        #pragma unroll
        for (int j = 0; j < 8; ++j)
            red[s][j] = (idx == s) ? fmaxf(acc[j], 0.f) : 0.f;

    #pragma unroll
    for (int msk = 8; msk <= 32; msk <<= 1)
        #pragma unroll
        for (int s = 0; s < 2; ++s)
            #pragma unroll
            for (int j = 0; j < 8; ++j)
                red[s][j] = fmaxf(red[s][j], __shfl_xor(red[s][j], msk));

    __shared__ float sm[4][2][64];
    const int wid  = threadIdx.x >> 6;
    const int lane = threadIdx.x & 63;
    if (lane < 8) {
        #pragma unroll
        for (int s = 0; s < 2; ++s)
            #pragma unroll
            for (int j = 0; j < 8; ++j)
                sm[wid][s][lane * 8 + j] = red[s][j];
    }
    __syncthreads();
    if (threadIdx.x < 128) {
        const int s = threadIdx.x >> 6;      // graph slot
        const int f = threadIdx.x & 63;      // feature within half
        if (s == 0 || glast != gbase) {
            float m = fmaxf(fmaxf(sm[0][s][f], sm[1][s][f]),
                            fmaxf(sm[2][s][f], sm[3][s][f]));
            atomicMax(pool + (size_t)(gbase + s) * HDIM + half * 64 + f,
                      __builtin_bit_cast(int, m));
        }
    }
}

// ---------------- f32 register-blocked GEMM (FF head only, tiny) ----------------
template<int K, int NC, bool OUT_RELU_BIAS>
__global__ __launch_bounds__(256) void k_gemm(
    const float* __restrict__ in, const float* __restrict__ W,
    const float* __restrict__ out_bias, float* __restrict__ out0, int M)
{
    constexpr int BK = 32;
    constexpr int TC = NC / 8;
    constexpr int TR = 256 / TC;
    constexpr int ROWS = TR * 8;
    constexpr int XST = ROWS + 4;

    __shared__ float xs[BK][XST];
    __shared__ float ws[BK][NC];

    const int tid = threadIdx.x;
    const int tc  = tid % TC;
    const int tr  = tid / TC;
    const int row0 = blockIdx.x * ROWS;

    float acc[8][8];
    #pragma unroll
    for (int i = 0; i < 8; ++i)
        #pragma unroll
        for (int j = 0; j < 8; ++j) acc[i][j] = 0.f;

    for (int k0 = 0; k0 < K; k0 += BK) {
        {
            constexpr int TASKS = BK * NC / 4;
            #pragma unroll
            for (int it = 0; it < TASKS / 256; ++it) {
                int t  = it * 256 + tid;
                int wk = t / (NC / 4);
                int wc = (t % (NC / 4)) * 4;
                *(float4*)(&ws[wk][wc]) = *(const float4*)(W + (size_t)(k0 + wk) * NC + wc);
            }
        }
        {
            constexpr int TASKS = ROWS * BK / 4;
            #pragma unroll
            for (int it = 0; it < TASKS / 256; ++it) {
                int t   = it * 256 + tid;
                int r   = t / (BK / 4);
                int kq  = (t % (BK / 4)) * 4;
                float4 x4 = *(const float4*)(in + (size_t)(row0 + r) * K + k0 + kq);
                xs[kq + 0][r] = x4.x; xs[kq + 1][r] = x4.y;
                xs[kq + 2][r] = x4.z; xs[kq + 3][r] = x4.w;
            }
        }
        __syncthreads();
        #pragma unroll 8
        for (int kk = 0; kk < BK; ++kk) {
            float a[8], b[8];
            #pragma unroll
            for (int i = 0; i < 8; ++i) a[i] = xs[kk][tr * 8 + i];
            #pragma unroll
            for (int j = 0; j < 8; ++j) b[j] = ws[kk][tc * 8 + j];
            #pragma unroll
            for (int i = 0; i < 8; ++i)
                #pragma unroll
                for (int j = 0; j < 8; ++j)
                    acc[i][j] = fmaf(a[i], b[j], acc[i][j]);
        }
        __syncthreads();
    }

    #pragma unroll
    for (int i = 0; i < 8; ++i) {
        const int row = row0 + tr * 8 + i;
        #pragma unroll
        for (int jq = 0; jq < 2; ++jq) {
            const int col = tc * 8 + jq * 4;
            float4 v;
            v.x = acc[i][jq * 4 + 0]; v.y = acc[i][jq * 4 + 1];
            v.z = acc[i][jq * 4 + 2]; v.w = acc[i][jq * 4 + 3];
            if constexpr (OUT_RELU_BIAS) {
                const float4 bb = *(const float4*)(out_bias + col);
                v.x = fmaxf(v.x + bb.x, 0.f); v.y = fmaxf(v.y + bb.y, 0.f);
                v.z = fmaxf(v.z + bb.z, 0.f); v.w = fmaxf(v.w + bb.w, 0.f);
            }
            *(float4*)(out0 + (size_t)row * NC + col) = v;
        }
    }
}

extern "C" void kernel_launch(void* const* d_in, const int* in_sizes, int n_in,
                              void* d_out, int out_size, void* d_ws, size_t ws_size,
                              hipStream_t stream) {
    const float* x    = (const float*)d_in[0];
    const int*   ei   = (const int*)d_in[1];
    const int*   batch= (const int*)d_in[2];
    const float* W0   = (const float*)d_in[3];
    const float* b0   = (const float*)d_in[4];
    const float* W1   = (const float*)d_in[5];
    const float* b1   = (const float*)d_in[6];
    const float* Wf0  = (const float*)d_in[7];
    const float* bf0  = (const float*)d_in[8];
    const float* Wf1  = (const float*)d_in[9];
    const float* bf1  = (const float*)d_in[10];
    float* out = (float*)d_out;

    const int* srcI = ei;
    const int* dstI = ei + NEDGES;

    constexpr int SCAN_NBLK = (NATOMS + 1023) / 1024;   // 391

    // workspace layout — ~291.2 MB (ws is ~499 MB per measured poison fill).
    //   rank aliases hwA (rank dead after k_fill; hwA first written by GEMM-1).
    //   xb now has its OWN region (fused layer-0 writes aggB while reading xb).
    char* base = (char*)d_ws;
    unsigned short* hwA  = (unsigned short*)(base + 0);              // N*128 bf16
    int*   rank      = (int*)(base + 0);                             // E ints (alias)
    unsigned short* aggB = (unsigned short*)(base + 102400000);      // N*128 bf16
    float* dinv      = (float*)(base + 204800000);                   // N f32
    int*   row_start = (int*)(base + 206400000);                     // N+1 ints
    int2*  csr_ev    = (int2*)(base + 208000064);                    // E int2
    int*   blockSums = (int*)(base + 220800064);                     // 512 ints
    float* pool      = (float*)(base + 220802112);                   // G*128 f32
    float* ff0       = (float*)(base + 222899264);                   // G*256 f32
    short* wf0       = (short*)(base + 227093568);                   // 24,576 B
    short* wf1       = (short*)(base + 227118144);                   // 32,768 B
    unsigned short* xb = (unsigned short*)(base + 227150912);        // N*80 bf16 = 64 MB

    // 1) degree (+rank) -> scan (+dinv) -> atomic-free CSR fill
    hipMemsetAsync(row_start, 0, (size_t)(NATOMS + 1) * sizeof(int), stream);
    hipMemsetAsync(pool, 0, (size_t)NGRAPH * HDIM * sizeof(float), stream);  // relu identity
    k_degi<<<(NEDGES + 255) / 256, 256, 0, stream>>>(dstI, row_start, rank, NEDGES);
    k_scan1<<<SCAN_NBLK, 256, 0, stream>>>(row_start, blockSums, dinv, NATOMS);
    k_scan2<<<1, 512, 0, stream>>>(blockSums, SCAN_NBLK);
    k_scan3<<<SCAN_NBLK, 256, 0, stream>>>(row_start, blockSums, NATOMS, NEDGES);
    k_fill<<<(NEDGES + 255) / 256, 256, 0, stream>>>(srcI, dstI, row_start, rank,
                                                     csr_ev, dinv, NEDGES);

    // 2) pack weights (W0 augmented: k=78 row carries b0) + pack x to bf16[80]
    k_packw<3, F_INN, true><<<8 * 3, 64, 0, stream>>>(W0, b0, wf0);
    k_packw<4, HDIM, false><<<8 * 4, 64, 0, stream>>>(W1, nullptr, wf1);
    k_packx<<<(NATOMS * 20 + 255) / 256, 256, 0, stream>>>(x, xb);

    // 3) layer 0 FUSED: gather(78-dim) + GEMM + bias(slot78) + relu -> aggB
    k_fused0<<<NATOMS / 32, 256, 0, stream>>>(xb, wf0, row_start, csr_ev, dinv,
                                              (short*)aggB);

    // 4) layer 1: hw1 = aggB@W1 ; gather fused with bias+relu+graph max-pool
    k_gemm_mfma<4, HDIM, false><<<1024, 256, 0, stream>>>((const short*)aggB, wf1,
                                                          (short*)hwA, NATOMS);
    k_gather_pool<<<NATOMS / 32, 256, 0, stream>>>(hwA, row_start, csr_ev,
                                                   dinv, b1, batch, (int*)pool, 0);
    k_gather_pool<<<NATOMS / 32, 256, 0, stream>>>(hwA, row_start, csr_ev,
                                                   dinv, b1, batch, (int*)pool, 1);

    // 5) FF head (f32, tiny)
    k_gemm<HDIM, FF0D, true><<<NGRAPH / 64, 256, 0, stream>>>(pool, Wf0, bf0, ff0, NGRAPH);
    k_gemm<FF0D, FF1D, true><<<NGRAPH / 128, 256, 0, stream>>>(ff0, Wf1, bf1, out, NGRAPH);
}

// Round 8
// 641.096 us; speedup vs baseline: 1.0266x; 1.0266x over previous
//
#include <hip/hip_runtime.h>
#include <cstdint>
#include <cstddef>

// Problem constants (fixed by the reference)
#define NATOMS 400000
#define NEDGES 1600000
#define NGRAPH 4096
#define F_INN  78
#define HDIM   128
#define FF0D   256
#define FF1D   128

// layer-0 packed-input row: 78 feats + pad, bf16, 80 slots (160B)
#define XPAD   80

typedef __attribute__((ext_vector_type(8))) short short8;   // 8 bf16 (4 VGPRs)
typedef __attribute__((ext_vector_type(4))) short short4v;  // 4 bf16 (8B store)
typedef __attribute__((ext_vector_type(4))) float f32x4;
typedef __attribute__((ext_vector_type(2))) float f32x2;

// f32 -> bf16 round-to-nearest-even (bit-level)
static __device__ __forceinline__ short f2bf(float f) {
    unsigned u = __builtin_bit_cast(unsigned, f);
    unsigned r = (u + 0x7fffu + ((u >> 16) & 1u)) >> 16;
    return (short)r;
}
static __device__ __forceinline__ float bf2f(unsigned short u) {
    return __builtin_bit_cast(float, ((unsigned)u) << 16);
}

// ---------------- degree + per-edge rank (atomic return value) ----------------
__global__ __launch_bounds__(256) void k_degi(const int* __restrict__ dst,
                                              int* __restrict__ deg,
                                              int* __restrict__ rank, int E) {
    int e = blockIdx.x * 256 + threadIdx.x;
    if (e < E) rank[e] = atomicAdd(&deg[dst[e]], 1);
}

// ---------------- exclusive scan over N ints (3 kernels, in-place) ----------------
// scan1 also emits dinv = rsqrt(deg+1) (deg still intact at entry)
__global__ __launch_bounds__(256) void k_scan1(int* __restrict__ data,
                                               int* __restrict__ blockSums,
                                               float* __restrict__ dinv, int n) {
    __shared__ int ts[256];
    const int base = blockIdx.x * 1024 + threadIdx.x * 4;
    int v[4];
    #pragma unroll
    for (int j = 0; j < 4; ++j) v[j] = (base + j < n) ? data[base + j] : 0;
    #pragma unroll
    for (int j = 0; j < 4; ++j)
        if (base + j < n) dinv[base + j] = rsqrtf((float)v[j] + 1.0f);
    const int tot = v[0] + v[1] + v[2] + v[3];
    ts[threadIdx.x] = tot;
    __syncthreads();
    #pragma unroll
    for (int off = 1; off < 256; off <<= 1) {
        int t = (threadIdx.x >= off) ? ts[threadIdx.x - off] : 0;
        __syncthreads();
        ts[threadIdx.x] += t;
        __syncthreads();
    }
    int run = ts[threadIdx.x] - tot;
    #pragma unroll
    for (int j = 0; j < 4; ++j) {
        if (base + j < n) data[base + j] = run;
        run += v[j];
    }
    if (threadIdx.x == 255) blockSums[blockIdx.x] = ts[255];
}

__global__ __launch_bounds__(512) void k_scan2(int* __restrict__ blockSums, int nb) {
    __shared__ int ts[512];
    int v = (threadIdx.x < nb) ? blockSums[threadIdx.x] : 0;
    ts[threadIdx.x] = v;
    __syncthreads();
    #pragma unroll
    for (int off = 1; off < 512; off <<= 1) {
        int t = (threadIdx.x >= off) ? ts[threadIdx.x - off] : 0;
        __syncthreads();
        ts[threadIdx.x] += t;
        __syncthreads();
    }
    if (threadIdx.x < nb) blockSums[threadIdx.x] = ts[threadIdx.x] - v;
}

__global__ __launch_bounds__(256) void k_scan3(int* __restrict__ data,
                                               const int* __restrict__ blockSums,
                                               int n, int total) {
    const int off = blockSums[blockIdx.x];
    const int base = blockIdx.x * 1024 + threadIdx.x * 4;
    #pragma unroll
    for (int j = 0; j < 4; ++j)
        if (base + j < n) data[base + j] += off;
    if (blockIdx.x == 0 && threadIdx.x == 0) data[n] = total;
}

// ---------------- CSR fill: atomic-free (pos = row_start[d] + rank[e]) ----------
__global__ __launch_bounds__(256) void k_fill(const int* __restrict__ src,
                                              const int* __restrict__ dst,
                                              const int* __restrict__ row_start,
                                              const int* __restrict__ rank,
                                              int2* __restrict__ csr_ev,
                                              const float* __restrict__ dinv, int E) {
    int e = blockIdx.x * 256 + threadIdx.x;
    if (e >= E) return;
    int d = dst[e];
    int s = src[e];
    int pos = row_start[d] + rank[e];
    float norm = dinv[s] * dinv[d];
    csr_ev[pos] = make_int2(s, __builtin_bit_cast(int, norm));
}

// ---------------- weight pack: W [KSRC][128] f32 -> MFMA A-fragment order bf16 ----
// A[feat][k]: lane&15 = feat-within-tile ct, k = kc*32 + (lane>>4)*8 + j
// If BIASROW: k == KSRC takes bias[n] (input rows carry constant 1.0 there).
template<int KC, int KSRC, bool BIASROW>
__global__ __launch_bounds__(64) void k_packw(const float* __restrict__ W,
                                              const float* __restrict__ b,
                                              short* __restrict__ wf) {
    int t = blockIdx.x * 64 + threadIdx.x;      // t = f*64 + lane
    int f = t >> 6, lane = t & 63;
    int ct = f / KC, kc = f % KC;
    int n  = ct * 16 + (lane & 15);
    int k0 = kc * 32 + (lane >> 4) * 8;
    short8 o;
    #pragma unroll
    for (int j = 0; j < 8; ++j) {
        int k = k0 + j;
        float v = 0.f;
        if (k < KSRC) v = W[(size_t)k * 128 + n];
        else if (BIASROW && k == KSRC) v = b[n];
        o[j] = f2bf(v);
    }
    *(short8*)(wf + (size_t)t * 8) = o;
}

// ---------------- x pack: [N][78] f32 -> [N][80] bf16 (slots 78,79 zero) --------
__global__ __launch_bounds__(256) void k_packx(const float* __restrict__ x,
                                               unsigned short* __restrict__ xb) {
    int t = blockIdx.x * 256 + threadIdx.x;     // N*20 tasks, 4 shorts each
    if (t >= NATOMS * 20) return;
    int n = t / 20, g = t % 20;
    const float* xr = x + (size_t)n * F_INN + g * 4;
    short4v o;
    if (g < 19) {
        f32x2 a = *(const f32x2*)(xr);
        f32x2 b = *(const f32x2*)(xr + 2);
        o.x = f2bf(a.x); o.y = f2bf(a.y); o.z = f2bf(b.x); o.w = f2bf(b.y);
    } else {                                    // feats 76,77 + two zero pads
        f32x2 a = *(const f32x2*)(xr);
        o.x = f2bf(a.x); o.y = f2bf(a.y); o.z = 0; o.w = 0;
    }
    *(short4v*)(xb + (size_t)n * XPAD + g * 4) = o;
}

// ---------------- FUSED layer 0: gather-aggregate (78-dim) + MFMA GEMM ----------
// One block = 32 nodes, 256 threads. Output aggB = relu((A_hat x)@W0 + b0).
__global__ __launch_bounds__(256) void k_fused0(
    const unsigned short* __restrict__ xb, const short* __restrict__ wfrag,
    const int* __restrict__ row_start, const int2* __restrict__ csr_ev,
    const float* __restrict__ dinv, short* __restrict__ outp)
{
    constexpr int XLDS = 104;                          // shorts per xs row (208B)
    __shared__ __align__(16) short lds_w[24 * 64 * 8];       // 24 KB W0 fragments
    __shared__ __align__(16) unsigned short xs[32 * XLDS];   // 6.5 KB
    __shared__ __align__(16) char lds_st[4 * 2048];          // 8 KB store tiles

    const int tid = threadIdx.x;
    // ---- stage W0 fragments (L2-hot broadcast) ----
    #pragma unroll
    for (int it = 0; it < 6; ++it) {
        int t = it * 256 + tid;
        *(short8*)(lds_w + (size_t)t * 8) = *(const short8*)(wfrag + (size_t)t * 8);
    }

    // ---- phase 1: gather-aggregate 32 nodes into xs ----
    {
        const int nl = tid >> 3;               // local node 0..31
        const int n  = blockIdx.x * 32 + nl;
        const int l  = tid & 7;
        const int c8 = l * 8;                  // head feats c8..c8+7
        const int ct = 64 + l * 2;             // tail feats ct, ct+1
        const float dv = dinv[n];
        const float d2 = dv * dv;

        float acc[8], tacc0, tacc1;
        {
            const short8 sv = *(const short8*)(xb + (size_t)n * XPAD + c8);
            const unsigned tv = *(const unsigned*)(xb + (size_t)n * XPAD + ct);
            #pragma unroll
            for (int j = 0; j < 8; ++j) acc[j] = bf2f((unsigned short)sv[j]) * d2;
            tacc0 = bf2f((unsigned short)(tv & 0xffff)) * d2;
            tacc1 = bf2f((unsigned short)(tv >> 16)) * d2;
        }

        const int s0 = row_start[n], s1 = row_start[n + 1];
        int i = s0;
        for (; i + 3 < s1; i += 4) {
            const int2 e0 = csr_ev[i];
            const int2 e1 = csr_ev[i + 1];
            const int2 e2 = csr_ev[i + 2];
            const int2 e3 = csr_ev[i + 3];
            const short8 r0 = *(const short8*)(xb + (size_t)e0.x * XPAD + c8);
            const short8 r1 = *(const short8*)(xb + (size_t)e1.x * XPAD + c8);
            const short8 r2 = *(const short8*)(xb + (size_t)e2.x * XPAD + c8);
            const short8 r3 = *(const short8*)(xb + (size_t)e3.x * XPAD + c8);
            const unsigned t0 = *(const unsigned*)(xb + (size_t)e0.x * XPAD + ct);
            const unsigned t1 = *(const unsigned*)(xb + (size_t)e1.x * XPAD + ct);
            const unsigned t2 = *(const unsigned*)(xb + (size_t)e2.x * XPAD + ct);
            const unsigned t3 = *(const unsigned*)(xb + (size_t)e3.x * XPAD + ct);
            const float w0 = __builtin_bit_cast(float, e0.y);
            const float w1 = __builtin_bit_cast(float, e1.y);
            const float w2 = __builtin_bit_cast(float, e2.y);
            const float w3 = __builtin_bit_cast(float, e3.y);
            #pragma unroll
            for (int j = 0; j < 8; ++j) acc[j] = fmaf(bf2f((unsigned short)r0[j]), w0, acc[j]);
            #pragma unroll
            for (int j = 0; j < 8; ++j) acc[j] = fmaf(bf2f((unsigned short)r1[j]), w1, acc[j]);
            #pragma unroll
            for (int j = 0; j < 8; ++j) acc[j] = fmaf(bf2f((unsigned short)r2[j]), w2, acc[j]);
            #pragma unroll
            for (int j = 0; j < 8; ++j) acc[j] = fmaf(bf2f((unsigned short)r3[j]), w3, acc[j]);
            tacc0 = fmaf(bf2f((unsigned short)(t0 & 0xffff)), w0, tacc0);
            tacc1 = fmaf(bf2f((unsigned short)(t0 >> 16)),    w0, tacc1);
            tacc0 = fmaf(bf2f((unsigned short)(t1 & 0xffff)), w1, tacc0);
            tacc1 = fmaf(bf2f((unsigned short)(t1 >> 16)),    w1, tacc1);
            tacc0 = fmaf(bf2f((unsigned short)(t2 & 0xffff)), w2, tacc0);
            tacc1 = fmaf(bf2f((unsigned short)(t2 >> 16)),    w2, tacc1);
            tacc0 = fmaf(bf2f((unsigned short)(t3 & 0xffff)), w3, tacc0);
            tacc1 = fmaf(bf2f((unsigned short)(t3 >> 16)),    w3, tacc1);
        }
        for (; i < s1; ++i) {
            const int2 e0 = csr_ev[i];
            const short8 r0 = *(const short8*)(xb + (size_t)e0.x * XPAD + c8);
            const unsigned t0 = *(const unsigned*)(xb + (size_t)e0.x * XPAD + ct);
            const float w0 = __builtin_bit_cast(float, e0.y);
            #pragma unroll
            for (int j = 0; j < 8; ++j) acc[j] = fmaf(bf2f((unsigned short)r0[j]), w0, acc[j]);
            tacc0 = fmaf(bf2f((unsigned short)(t0 & 0xffff)), w0, tacc0);
            tacc1 = fmaf(bf2f((unsigned short)(t0 >> 16)),    w0, tacc1);
        }

        short8 o;
        #pragma unroll
        for (int j = 0; j < 8; ++j) o[j] = f2bf(acc[j]);
        *(short8*)(xs + nl * XLDS + c8) = o;
        unsigned to;
        if (l == 7) to = 0x00003F80u;      // slot78 = bf16(1.0), slot79 = 0
        else {
            to = (unsigned)(unsigned short)f2bf(tacc0) |
                 ((unsigned)(unsigned short)f2bf(tacc1) << 16);
        }
        *(unsigned*)(xs + nl * XLDS + ct) = to;
        *(unsigned*)(xs + nl * XLDS + 80 + l * 2) = 0u;   // zero k=80..95 (kc=2 tail)
    }
    __syncthreads();

    // ---- phase 2: MFMA ----
    const int lane = tid & 63;
    const int wid  = tid >> 6;
    const int m = lane & 15, q = lane >> 4;
    const int T  = wid >> 1;               // 16-node tile 0/1
    const int c0 = (wid & 1) * 4;          // ct half

    short8 afr[3];
    #pragma unroll
    for (int kc = 0; kc < 3; ++kc)
        afr[kc] = *(const short8*)(xs + (T * 16 + m) * XLDS + kc * 32 + q * 8);

    f32x4 acc[4];
    #pragma unroll
    for (int cc = 0; cc < 4; ++cc) acc[cc] = (f32x4){0.f, 0.f, 0.f, 0.f};
    #pragma unroll
    for (int kc = 0; kc < 3; ++kc)
        #pragma unroll
        for (int cc = 0; cc < 4; ++cc) {
            const short8 wv = *(const short8*)(lds_w + ((size_t)(((c0 + cc) * 3 + kc) * 64 + lane)) * 8);
            acc[cc] = __builtin_amdgcn_mfma_f32_16x16x32_bf16(wv, afr[kc], acc[cc], 0, 0, 0);
        }

    // relu + bf16, wave-private swizzled store tile, then 2x 1KB bursts
    char* const st = lds_st + wid * 2048;
    #pragma unroll
    for (int cc = 0; cc < 4; ++cc) {
        short4v o;
        o.x = f2bf(fmaxf(acc[cc][0], 0.f));
        o.y = f2bf(fmaxf(acc[cc][1], 0.f));
        o.z = f2bf(fmaxf(acc[cc][2], 0.f));
        o.w = f2bf(fmaxf(acc[cc][3], 0.f));
        const int c = (cc * 32 + q * 8) ^ ((m & 7) << 4);
        *(short4v*)(st + m * 128 + c) = o;
    }
    #pragma unroll
    for (int p = 0; p < 2; ++p) {
        const int r  = p * 8 + (lane >> 3);
        const int cb = ((lane & 7) * 16) ^ ((r & 7) << 4);
        const short8 v = *(const short8*)(st + r * 128 + cb);
        *(short8*)(outp + (size_t)(blockIdx.x * 32 + T * 16 + r) * 128
                        + c0 * 16 + (lane & 7) * 8) = v;
    }
}

// ---------------- FUSED layer 1: gather (128-dim) + MFMA + bias + relu + POOL ----
// One block = 64 nodes, 512 threads (8 waves). Reassociated: A_hat(H@W1) =
// (A_hat H)@W1, so gather runs on aggB directly and the GEMM epilogue does
// bias+relu+graph-max-pool -> atomicMax. NO hw intermediate (saves 102MB write
// + ~230MB random re-read + one csr pass vs the unfused pipeline).
__global__ __launch_bounds__(512) void k_fused1(
    const unsigned short* __restrict__ hw, const short* __restrict__ wfrag,
    const int* __restrict__ row_start, const int2* __restrict__ csr_ev,
    const float* __restrict__ dinv, const float* __restrict__ bias,
    const int* __restrict__ batch, int* __restrict__ pool)
{
    constexpr int XL = 136;                            // shorts per xs row (272B)
    __shared__ __align__(16) short lds_w[32 * 64 * 8];       // 32 KB W1 fragments
    __shared__ __align__(16) unsigned short xs[64 * XL];     // 17.4 KB

    const int tid = threadIdx.x;
    // ---- stage W1 fragments ----
    #pragma unroll
    for (int it = 0; it < 4; ++it) {
        int t = it * 512 + tid;
        *(short8*)(lds_w + (size_t)t * 8) = *(const short8*)(wfrag + (size_t)t * 8);
    }

    // ---- phase 1: gather-aggregate 64 nodes (full 128 feats) into xs ----
    {
        const int nl = tid >> 3;               // local node 0..63
        const int n  = blockIdx.x * 64 + nl;
        const int l  = tid & 7;
        const int cA = l * 8;                  // feats cA..cA+7
        const int cB = 64 + l * 8;             // feats cB..cB+7
        const float dv = dinv[n];
        const float d2 = dv * dv;

        float aA[8], aB[8];
        {
            const short8 sa = *(const short8*)(hw + (size_t)n * HDIM + cA);
            const short8 sb = *(const short8*)(hw + (size_t)n * HDIM + cB);
            #pragma unroll
            for (int j = 0; j < 8; ++j) {
                aA[j] = bf2f((unsigned short)sa[j]) * d2;
                aB[j] = bf2f((unsigned short)sb[j]) * d2;
            }
        }

        const int s0 = row_start[n], s1 = row_start[n + 1];
        int i = s0;
        for (; i + 1 < s1; i += 2) {
            const int2 e0 = csr_ev[i];
            const int2 e1 = csr_ev[i + 1];
            const short8 rA0 = *(const short8*)(hw + (size_t)e0.x * HDIM + cA);
            const short8 rB0 = *(const short8*)(hw + (size_t)e0.x * HDIM + cB);
            const short8 rA1 = *(const short8*)(hw + (size_t)e1.x * HDIM + cA);
            const short8 rB1 = *(const short8*)(hw + (size_t)e1.x * HDIM + cB);
            const float w0 = __builtin_bit_cast(float, e0.y);
            const float w1 = __builtin_bit_cast(float, e1.y);
            #pragma unroll
            for (int j = 0; j < 8; ++j) {
                aA[j] = fmaf(bf2f((unsigned short)rA0[j]), w0, aA[j]);
                aB[j] = fmaf(bf2f((unsigned short)rB0[j]), w0, aB[j]);
            }
            #pragma unroll
            for (int j = 0; j < 8; ++j) {
                aA[j] = fmaf(bf2f((unsigned short)rA1[j]), w1, aA[j]);
                aB[j] = fmaf(bf2f((unsigned short)rB1[j]), w1, aB[j]);
            }
        }
        for (; i < s1; ++i) {
            const int2 e0 = csr_ev[i];
            const short8 rA0 = *(const short8*)(hw + (size_t)e0.x * HDIM + cA);
            const short8 rB0 = *(const short8*)(hw + (size_t)e0.x * HDIM + cB);
            const float w0 = __builtin_bit_cast(float, e0.y);
            #pragma unroll
            for (int j = 0; j < 8; ++j) {
                aA[j] = fmaf(bf2f((unsigned short)rA0[j]), w0, aA[j]);
                aB[j] = fmaf(bf2f((unsigned short)rB0[j]), w0, aB[j]);
            }
        }

        short8 oA, oB;
        #pragma unroll
        for (int j = 0; j < 8; ++j) { oA[j] = f2bf(aA[j]); oB[j] = f2bf(aB[j]); }
        *(short8*)(xs + nl * XL + cA) = oA;
        *(short8*)(xs + nl * XL + cB) = oB;
    }
    __syncthreads();

    // ---- phase 2: MFMA (4 node-tiles x 2 ct-halves across 8 waves) ----
    const int lane = tid & 63;
    const int wid  = tid >> 6;             // 0..7
    const int m = lane & 15, q = lane >> 4;
    const int T  = wid >> 1;               // node tile 0..3
    const int c0 = (wid & 1) * 4;          // ct half (4 ct each)

    short8 afr[4];
    #pragma unroll
    for (int kc = 0; kc < 4; ++kc)
        afr[kc] = *(const short8*)(xs + (T * 16 + m) * XL + kc * 32 + q * 8);

    f32x4 acc[4];
    #pragma unroll
    for (int cc = 0; cc < 4; ++cc) acc[cc] = (f32x4){0.f, 0.f, 0.f, 0.f};
    #pragma unroll
    for (int kc = 0; kc < 4; ++kc)
        #pragma unroll
        for (int cc = 0; cc < 4; ++cc) {
            const short8 wv = *(const short8*)(lds_w + ((size_t)(((c0 + cc) * 4 + kc) * 64 + lane)) * 8);
            acc[cc] = __builtin_amdgcn_mfma_f32_16x16x32_bf16(wv, afr[kc], acc[cc], 0, 0, 0);
        }

    // ---- epilogue: bias + relu + per-graph max over nodes + atomicMax ----
    const int nb    = blockIdx.x * 64;
    const int gbase = batch[nb];                       // uniform
    const int glast = batch[nb + 63];                  // uniform
    const int idx   = batch[nb + T * 16 + m] - gbase;  // 0 or 1

    float v[16];
    #pragma unroll
    for (int cc = 0; cc < 4; ++cc) {
        const f32x4 b4 = *(const f32x4*)(bias + (c0 + cc) * 16 + q * 4);
        #pragma unroll
        for (int j = 0; j < 4; ++j)
            v[cc * 4 + j] = fmaxf(acc[cc][j] + b4[j], 0.f);
    }

    // slot 0 (graph gbase)
    {
        float r[16];
        #pragma unroll
        for (int k = 0; k < 16; ++k) r[k] = (idx == 0) ? v[k] : 0.f;
        #pragma unroll
        for (int msk = 1; msk <= 8; msk <<= 1)
            #pragma unroll
            for (int k = 0; k < 16; ++k)
                r[k] = fmaxf(r[k], __shfl_xor(r[k], msk));
        if (m == 0) {
            #pragma unroll
            for (int cc = 0; cc < 4; ++cc)
                #pragma unroll
                for (int j = 0; j < 4; ++j)
                    atomicMax(pool + (size_t)gbase * HDIM + (c0 + cc) * 16 + q * 4 + j,
                              __builtin_bit_cast(int, r[cc * 4 + j]));
        }
    }
    // slot 1 (graph gbase+1), only for boundary blocks
    if (glast != gbase) {
        float r[16];
        #pragma unroll
        for (int k = 0; k < 16; ++k) r[k] = (idx == 1) ? v[k] : 0.f;
        #pragma unroll
        for (int msk = 1; msk <= 8; msk <<= 1)
            #pragma unroll
            for (int k = 0; k < 16; ++k)
                r[k] = fmaxf(r[k], __shfl_xor(r[k], msk));
        if (m == 0) {
            #pragma unroll
            for (int cc = 0; cc < 4; ++cc)
                #pragma unroll
                for (int j = 0; j < 4; ++j)
                    atomicMax(pool + (size_t)(gbase + 1) * HDIM + (c0 + cc) * 16 + q * 4 + j,
                              __builtin_bit_cast(int, r[cc * 4 + j]));
        }
    }
}

// ---------------- f32 register-blocked GEMM (FF head only, tiny) ----------------
template<int K, int NC, bool OUT_RELU_BIAS>
__global__ __launch_bounds__(256) void k_gemm(
    const float* __restrict__ in, const float* __restrict__ W,
    const float* __restrict__ out_bias, float* __restrict__ out0, int M)
{
    constexpr int BK = 32;
    constexpr int TC = NC / 8;
    constexpr int TR = 256 / TC;
    constexpr int ROWS = TR * 8;
    constexpr int XST = ROWS + 4;

    __shared__ float xs[BK][XST];
    __shared__ float ws[BK][NC];

    const int tid = threadIdx.x;
    const int tc  = tid % TC;
    const int tr  = tid / TC;
    const int row0 = blockIdx.x * ROWS;

    float acc[8][8];
    #pragma unroll
    for (int i = 0; i < 8; ++i)
        #pragma unroll
        for (int j = 0; j < 8; ++j) acc[i][j] = 0.f;

    for (int k0 = 0; k0 < K; k0 += BK) {
        {
            constexpr int TASKS = BK * NC / 4;
            #pragma unroll
            for (int it = 0; it < TASKS / 256; ++it) {
                int t  = it * 256 + tid;
                int wk = t / (NC / 4);
                int wc = (t % (NC / 4)) * 4;
                *(float4*)(&ws[wk][wc]) = *(const float4*)(W + (size_t)(k0 + wk) * NC + wc);
            }
        }
        {
            constexpr int TASKS = ROWS * BK / 4;
            #pragma unroll
            for (int it = 0; it < TASKS / 256; ++it) {
                int t   = it * 256 + tid;
                int r   = t / (BK / 4);
                int kq  = (t % (BK / 4)) * 4;
                float4 x4 = *(const float4*)(in + (size_t)(row0 + r) * K + k0 + kq);
                xs[kq + 0][r] = x4.x; xs[kq + 1][r] = x4.y;
                xs[kq + 2][r] = x4.z; xs[kq + 3][r] = x4.w;
            }
        }
        __syncthreads();
        #pragma unroll 8
        for (int kk = 0; kk < BK; ++kk) {
            float a[8], b[8];
            #pragma unroll
            for (int i = 0; i < 8; ++i) a[i] = xs[kk][tr * 8 + i];
            #pragma unroll
            for (int j = 0; j < 8; ++j) b[j] = ws[kk][tc * 8 + j];
            #pragma unroll
            for (int i = 0; i < 8; ++i)
                #pragma unroll
                for (int j = 0; j < 8; ++j)
                    acc[i][j] = fmaf(a[i], b[j], acc[i][j]);
        }
        __syncthreads();
    }

    #pragma unroll
    for (int i = 0; i < 8; ++i) {
        const int row = row0 + tr * 8 + i;
        #pragma unroll
        for (int jq = 0; jq < 2; ++jq) {
            const int col = tc * 8 + jq * 4;
            float4 v;
            v.x = acc[i][jq * 4 + 0]; v.y = acc[i][jq * 4 + 1];
            v.z = acc[i][jq * 4 + 2]; v.w = acc[i][jq * 4 + 3];
            if constexpr (OUT_RELU_BIAS) {
                const float4 bb = *(const float4*)(out_bias + col);
                v.x = fmaxf(v.x + bb.x, 0.f); v.y = fmaxf(v.y + bb.y, 0.f);
                v.z = fmaxf(v.z + bb.z, 0.f); v.w = fmaxf(v.w + bb.w, 0.f);
            }
            *(float4*)(out0 + (size_t)row * NC + col) = v;
        }
    }
}

extern "C" void kernel_launch(void* const* d_in, const int* in_sizes, int n_in,
                              void* d_out, int out_size, void* d_ws, size_t ws_size,
                              hipStream_t stream) {
    const float* x    = (const float*)d_in[0];
    const int*   ei   = (const int*)d_in[1];
    const int*   batch= (const int*)d_in[2];
    const float* W0   = (const float*)d_in[3];
    const float* b0   = (const float*)d_in[4];
    const float* W1   = (const float*)d_in[5];
    const float* b1   = (const float*)d_in[6];
    const float* Wf0  = (const float*)d_in[7];
    const float* bf0  = (const float*)d_in[8];
    const float* Wf1  = (const float*)d_in[9];
    const float* bf1  = (const float*)d_in[10];
    float* out = (float*)d_out;

    const int* srcI = ei;
    const int* dstI = ei + NEDGES;

    constexpr int SCAN_NBLK = (NATOMS + 1023) / 1024;   // 391

    // workspace layout — ~291.2 MB (ws is ~499 MB per measured poison fill).
    //   rank aliases base+0 (dead after k_fill; nothing else lives there now
    //   that hwA is eliminated).
    char* base = (char*)d_ws;
    int*   rank      = (int*)(base + 0);                             // E ints
    unsigned short* aggB = (unsigned short*)(base + 102400000);      // N*128 bf16
    float* dinv      = (float*)(base + 204800000);                   // N f32
    int*   row_start = (int*)(base + 206400000);                     // N+1 ints
    int2*  csr_ev    = (int2*)(base + 208000064);                    // E int2
    int*   blockSums = (int*)(base + 220800064);                     // 512 ints
    float* pool      = (float*)(base + 220802112);                   // G*128 f32
    float* ff0       = (float*)(base + 222899264);                   // G*256 f32
    short* wf0       = (short*)(base + 227093568);                   // 24,576 B
    short* wf1       = (short*)(base + 227118144);                   // 32,768 B
    unsigned short* xb = (unsigned short*)(base + 227150912);        // N*80 bf16 = 64 MB

    // 1) degree (+rank) -> scan (+dinv) -> atomic-free CSR fill
    hipMemsetAsync(row_start, 0, (size_t)(NATOMS + 1) * sizeof(int), stream);
    hipMemsetAsync(pool, 0, (size_t)NGRAPH * HDIM * sizeof(float), stream);  // relu identity
    k_degi<<<(NEDGES + 255) / 256, 256, 0, stream>>>(dstI, row_start, rank, NEDGES);
    k_scan1<<<SCAN_NBLK, 256, 0, stream>>>(row_start, blockSums, dinv, NATOMS);
    k_scan2<<<1, 512, 0, stream>>>(blockSums, SCAN_NBLK);
    k_scan3<<<SCAN_NBLK, 256, 0, stream>>>(row_start, blockSums, NATOMS, NEDGES);
    k_fill<<<(NEDGES + 255) / 256, 256, 0, stream>>>(srcI, dstI, row_start, rank,
                                                     csr_ev, dinv, NEDGES);

    // 2) pack weights (W0 augmented: k=78 row carries b0) + pack x to bf16[80]
    k_packw<3, F_INN, true><<<8 * 3, 64, 0, stream>>>(W0, b0, wf0);
    k_packw<4, HDIM, false><<<8 * 4, 64, 0, stream>>>(W1, nullptr, wf1);
    k_packx<<<(NATOMS * 20 + 255) / 256, 256, 0, stream>>>(x, xb);

    // 3) layer 0 FUSED: gather(78-dim) + GEMM + bias(slot78) + relu -> aggB
    k_fused0<<<NATOMS / 32, 256, 0, stream>>>(xb, wf0, row_start, csr_ev, dinv,
                                              (short*)aggB);

    // 4) layer 1 FUSED: gather(128-dim over aggB) + GEMM + b1 + relu + max-pool
    k_fused1<<<NATOMS / 64, 512, 0, stream>>>(aggB, wf1, row_start, csr_ev,
                                              dinv, b1, batch, (int*)pool);

    // 5) FF head (f32, tiny)
    k_gemm<HDIM, FF0D, true><<<NGRAPH / 64, 256, 0, stream>>>(pool, Wf0, bf0, ff0, NGRAPH);
    k_gemm<FF0D, FF1D, true><<<NGRAPH / 128, 256, 0, stream>>>(ff0, Wf1, bf1, out, NGRAPH);
}